// Round 3
// baseline (1314.981 us; speedup 1.0000x reference)
//
#include <hip/hip_runtime.h>

#define B_    4
#define N_    20000
#define M_    20000
#define K_    16
#define CIN   64
#define CMID  16
#define COUT  67          // CIN + 3 additional channels
#define PPB   4           // one point per wave, 4 waves per block

typedef float float4_ __attribute__((ext_vector_type(4)));

__global__ __launch_bounds__(256, 4) void pconv_kernel(
    const float* __restrict__ in_feats,   // [B, N, 64]
    const int*   __restrict__ inds,       // [B, M, 16]
    const float* __restrict__ wn,         // [B, M, 16, 16]
    const float* __restrict__ addl,       // [B, M, 16, 3]
    float*       __restrict__ out)        // [B, M, 1072]
{
    __shared__ float lds_wn[PPB][K_ * CMID];   // 1 KB per wave

    const int tid  = threadIdx.x;
    const int lane = tid & 63;
    const int wav  = tid >> 6;

    int bp = blockIdx.x * PPB + wav;           // one point per wave
    bp = __builtin_amdgcn_readfirstlane(bp);   // force SGPR addressing
    const int b = bp / M_;

    const int*   pinds = inds + (long)bp * K_;
    const float* pwn   = wn   + (long)bp * (K_ * CMID);
    const float* padd  = addl + (long)bp * (K_ * 3);
    const float* bfeat = in_feats + (long)b * N_ * CIN;

    // ---- stage wn into LDS: one coalesced 1KB load + one ds_write_b128 ----
    float4_ wv_mine = ((const float4_*)pwn)[lane];
    *(float4_*)(&lds_wn[wav][lane * 4]) = wv_mine;
    // (same-wave write->read: compiler inserts lgkmcnt wait; no barrier needed,
    //  each wave only reads its own slot)

    // ---- uniform loads: 16 neighbor indices (s_load) ----
    int idxs[K_];
    #pragma unroll
    for (int k = 0; k < K_; ++k) idxs[k] = pinds[k];

    float4_ acc[4];                    // out[c=lane][w = 4q..4q+3]
    acc[0] = acc[1] = acc[2] = acc[3] = (float4_)0.f;
    float acc2 = 0.f;                  // tail: c = 64+(lane>>4), w = lane&15 (lane<48)
    const int g  = lane >> 4;
    const int wt = lane & 15;

    #pragma unroll
    for (int k = 0; k < K_; ++k) {
        // one fully-coalesced 256B gather per k; SGPR base, addresses all
        // available right after the idx s_load -> deep pipelining
        const float f = bfeat[(long)idxs[k] * CIN + lane];

        // uniform-address LDS broadcasts of wn[k][*]
        const float* lw = &lds_wn[wav][k * CMID];
        float4_ w0 = *(const float4_*)(lw + 0);
        float4_ w1 = *(const float4_*)(lw + 4);
        float4_ w2 = *(const float4_*)(lw + 8);
        float4_ w3 = *(const float4_*)(lw + 12);

        acc[0] += f * w0;
        acc[1] += f * w1;
        acc[2] += f * w2;
        acc[3] += f * w3;

        // tail channels: addl uniform scalars (s_load) + per-lane wn from LDS
        float a0 = padd[k * 3 + 0];
        float a1 = padd[k * 3 + 1];
        float a2 = padd[k * 3 + 2];
        float av = (g == 0) ? a0 : (g == 1) ? a1 : (g == 2) ? a2 : 0.f;
        float wv = lds_wn[wav][k * CMID + wt];     // 16 addrs over 16 banks, conflict-free
        acc2 += av * wv;
    }

    // ---- stores: lane owns its c-row (16 consecutive floats) ----
    float* pout = out + (long)bp * (COUT * CMID) + lane * CMID;
    *(float4_*)(pout + 0)  = acc[0];
    *(float4_*)(pout + 4)  = acc[1];
    *(float4_*)(pout + 8)  = acc[2];
    *(float4_*)(pout + 12) = acc[3];
    if (lane < 48) {
        out[(long)bp * (COUT * CMID) + (CIN + g) * CMID + wt] = acc2;
    }
}

extern "C" void kernel_launch(void* const* d_in, const int* in_sizes, int n_in,
                              void* d_out, int out_size, void* d_ws, size_t ws_size,
                              hipStream_t stream) {
    const float* in_feats = (const float*)d_in[0];
    const int*   ninds    = (const int*)d_in[1];
    const float* wn       = (const float*)d_in[2];
    const float* addl     = (const float*)d_in[3];
    float*       out      = (float*)d_out;

    const int total_points = B_ * M_;            // 80000
    dim3 grid(total_points / PPB);               // 20000 blocks, 1 point/wave
    dim3 block(256);
    pconv_kernel<<<grid, block, 0, stream>>>(in_feats, ninds, wn, addl, out);
}

// Round 4
// 164.845 us; speedup vs baseline: 7.9771x; 7.9771x over previous
//
#include <hip/hip_runtime.h>

#define B_    4
#define N_    20000
#define M_    20000
#define K_    16
#define CIN   64
#define CMID  16
#define COUT  67            // CIN + 3 additional channels
#define PPB   4             // one point per wave, 4 waves per block
#define LSTR  17            // LDS row stride in f32 (16 + 1 pad -> conflict-free)

typedef float float4_ __attribute__((ext_vector_type(4)));

__global__ __launch_bounds__(256, 6) void pconv_kernel(
    const float* __restrict__ in_feats,   // [B, N, 64]
    const int*   __restrict__ inds,       // [B, M, 16]
    const float* __restrict__ wn,         // [B, M, 16, 16]
    const float* __restrict__ addl,       // [B, M, 16, 3]
    float*       __restrict__ out)        // [B, M, 1072]
{
    // wave-private LDS: padded transpose buffer + wn copy for the tail phase
    __shared__ float lds_out[PPB][(COUT + 1) * LSTR];   // 4 x 4624 B
    __shared__ float lds_wn [PPB][K_ * CMID];           // 4 x 1 KB

    const int tid  = threadIdx.x;
    const int lane = tid & 63;
    const int wav  = tid >> 6;

    int bp = __builtin_amdgcn_readfirstlane(blockIdx.x * PPB + wav);
    const int b = bp / M_;                              // scalar magic-div

    const int*   pinds = inds + bp * K_;
    const float* pwn   = wn   + (long)bp * (K_ * CMID);
    const float* padd  = addl + (long)bp * (K_ * 3);
    const float* bfeat = in_feats + (long)b * N_ * CIN;

    // stage wn into LDS (tail phase only): 1 coalesced 1KB load + 1 ds_write_b128
    float4_ wstage = ((const float4_*)pwn)[lane];
    *(float4_*)(&lds_wn[wav][lane * 4]) = wstage;

    // all 16 neighbor indices -> SGPRs (one s_load_dwordx16 worth)
    int idxs[K_];
    #pragma unroll
    for (int k = 0; k < K_; ++k) idxs[k] = pinds[k];

    // main accumulation: lane owns channel c = lane, all 16 w outputs.
    // wn values are wave-uniform -> SGPR operands, no vector loads.
    float acc[CMID];
    #pragma unroll
    for (int w = 0; w < CMID; ++w) acc[w] = 0.f;

    #pragma unroll 4
    for (int k = 0; k < K_; ++k) {
        const float f = bfeat[(long)idxs[k] * CIN + lane];   // one 256B coalesced load
        #pragma unroll
        for (int w = 0; w < CMID; ++w)
            acc[w] += f * pwn[k * CMID + w];                 // s_load, uniform
    }

    // ---- transpose via padded LDS (stride 17 f32: all accesses <=2-way banks) ----
    float* lo = &lds_out[wav][0];
    #pragma unroll
    for (int w = 0; w < CMID; ++w)
        lo[lane * LSTR + w] = acc[w];                        // b32, banks 17*l%32: conflict-free

    // tail channels c = 64+t: lanes 0..47, t = lane>>4, wt = lane&15
    const int t  = lane >> 4;
    const int wt = lane & 15;
    if (lane < 48) {
        float acc2 = 0.f;
        #pragma unroll 4
        for (int k = 0; k < K_; ++k) {
            float a0 = padd[k * 3 + 0];                      // uniform s_loads
            float a1 = padd[k * 3 + 1];
            float a2 = padd[k * 3 + 2];
            float av = (t == 0) ? a0 : (t == 1) ? a1 : a2;   // 2 cndmask
            acc2 += av * lds_wn[wav][k * CMID + wt];         // 16 banks, broadcast x3
        }
        lo[(CIN + t) * LSTR + wt] = acc2;
    }

    // ---- readback in store-contiguous order; stores are 4x1KB + 192B contiguous ----
    float* pout = out + (long)bp * (COUT * CMID);
    const int q = lane >> 2;            // c within 16-row group
    const int r = lane & 3;             // float4 slot within c-row
    #pragma unroll
    for (int p = 0; p < 4; ++p) {
        const float* src = lo + (p * 16 + q) * LSTR + 4 * r;
        float4_ v = { src[0], src[1], src[2], src[3] };      // b32 reads (stride-17 safe)
        *(float4_*)(pout + p * 256 + lane * 4) = v;          // 64 lanes x 16B contiguous
    }
    if (lane < 12) {
        const float* src = lo + (CIN + q) * LSTR + 4 * r;
        float4_ v = { src[0], src[1], src[2], src[3] };
        *(float4_*)(pout + 1024 + lane * 4) = v;             // 192B contiguous
    }
}

extern "C" void kernel_launch(void* const* d_in, const int* in_sizes, int n_in,
                              void* d_out, int out_size, void* d_ws, size_t ws_size,
                              hipStream_t stream) {
    const float* in_feats = (const float*)d_in[0];
    const int*   ninds    = (const int*)d_in[1];
    const float* wn       = (const float*)d_in[2];
    const float* addl     = (const float*)d_in[3];
    float*       out      = (float*)d_out;

    const int total_points = B_ * M_;            // 80000
    dim3 grid(total_points / PPB);               // 20000 blocks, 1 point/wave
    dim3 block(256);
    pconv_kernel<<<grid, block, 0, stream>>>(in_feats, ninds, wn, addl, out);
}

// Round 5
// 129.105 us; speedup vs baseline: 10.1854x; 1.2768x over previous
//
#include <hip/hip_runtime.h>

#define B_    4
#define N_    20000
#define M_    20000
#define K_    16
#define CIN   64
#define CMID  16
#define COUT  67            // CIN + 3 additional channels
#define PPB   4             // one point per wave, 4 waves per block
#define LSTR  17            // LDS transpose row stride in f32 (16+1 pad)
#define NXCD  8

typedef float float4_ __attribute__((ext_vector_type(4)));

__global__ __launch_bounds__(256, 6) void pconv_kernel(
    const float* __restrict__ in_feats,   // [B, N, 64]
    const int*   __restrict__ inds,       // [B, M, 16]
    const float* __restrict__ wn,         // [B, M, 16, 16]
    const float* __restrict__ addl,       // [B, M, 16, 3]
    float*       __restrict__ out)        // [B, M, 1072]
{
    __shared__ float lds_out[PPB][(COUT + 1) * LSTR];   // 4 x 4624 B transpose buf
    __shared__ float lds_wn [PPB][K_ * CMID];           // 4 x 1 KB wn copy

    const int tid  = threadIdx.x;
    const int lane = tid & 63;
    const int wav  = tid >> 6;

    // bijective XCD swizzle: 20000 blocks -> 2500 contiguous per XCD
    const int nwg  = gridDim.x;
    const int q_   = nwg / NXCD;                         // 2500
    const int swz  = (blockIdx.x % NXCD) * q_ + blockIdx.x / NXCD;

    int bp = __builtin_amdgcn_readfirstlane(swz * PPB + wav);
    const int b = bp / M_;

    const int*   pinds = inds + bp * K_;
    const float* pwn   = wn   + (long)bp * (K_ * CMID);
    const float* padd  = addl + (long)bp * (K_ * 3);
    const float* bfeat = in_feats + (long)b * N_ * CIN;

    // ---- issue wn vector load (1KB coalesced) first ----
    float4_ wstage = ((const float4_*)pwn)[lane];

    // ---- 16 neighbor indices -> SGPRs ----
    int idxs[K_];
    #pragma unroll
    for (int k = 0; k < K_; ++k) idxs[k] = pinds[k];

    // ---- issue ALL 16 gathers before any consumption (max MLP) ----
    float f[K_];
    #pragma unroll
    for (int k = 0; k < K_; ++k)
        f[k] = bfeat[(long)idxs[k] * CIN + lane];        // 256B coalesced each

    // stage wn to LDS (waits only on wstage's own vmcnt slot)
    *(float4_*)(&lds_wn[wav][lane * 4]) = wstage;

    // ---- FMA phase: wn via uniform ds_read_b128 broadcasts ----
    float acc[CMID];
    #pragma unroll
    for (int w = 0; w < CMID; ++w) acc[w] = 0.f;

    #pragma unroll
    for (int k = 0; k < K_; ++k) {
        const float* lw = &lds_wn[wav][k * CMID];
        float4_ w0 = *(const float4_*)(lw + 0);
        float4_ w1 = *(const float4_*)(lw + 4);
        float4_ w2 = *(const float4_*)(lw + 8);
        float4_ w3 = *(const float4_*)(lw + 12);
        #pragma unroll
        for (int e = 0; e < 4; ++e) {
            acc[0  + e] += f[k] * w0[e];
            acc[4  + e] += f[k] * w1[e];
            acc[8  + e] += f[k] * w2[e];
            acc[12 + e] += f[k] * w3[e];
        }
    }

    // ---- transpose via padded LDS (17-f32 stride: <=2-way banks, free) ----
    float* lo = &lds_out[wav][0];
    #pragma unroll
    for (int w = 0; w < CMID; ++w)
        lo[lane * LSTR + w] = acc[w];

    // tail channels c = 64+t (t=lane>>4, wt=lane&15), lanes 0..47
    const int t  = lane >> 4;
    const int wt = lane & 15;
    if (lane < 48) {
        float acc2 = 0.f;
        #pragma unroll
        for (int k = 0; k < K_; ++k) {
            float a0 = padd[k * 3 + 0];                  // uniform s_loads
            float a1 = padd[k * 3 + 1];
            float a2 = padd[k * 3 + 2];
            float av = (t == 0) ? a0 : (t == 1) ? a1 : a2;
            acc2 += av * lds_wn[wav][k * CMID + wt];     // broadcast x3, conflict-free
        }
        lo[(CIN + t) * LSTR + wt] = acc2;
    }

    // ---- readback in store-contiguous order; stores 4x1KB + 192B ----
    float* pout = out + (long)bp * (COUT * CMID);
    const int q = lane >> 2;
    const int r = lane & 3;
    #pragma unroll
    for (int p = 0; p < 4; ++p) {
        const float* src = lo + (p * 16 + q) * LSTR + 4 * r;
        float4_ v = { src[0], src[1], src[2], src[3] };
        *(float4_*)(pout + p * 256 + lane * 4) = v;
    }
    if (lane < 12) {
        const float* src = lo + (CIN + q) * LSTR + 4 * r;
        float4_ v = { src[0], src[1], src[2], src[3] };
        *(float4_*)(pout + 1024 + lane * 4) = v;
    }
}

extern "C" void kernel_launch(void* const* d_in, const int* in_sizes, int n_in,
                              void* d_out, int out_size, void* d_ws, size_t ws_size,
                              hipStream_t stream) {
    const float* in_feats = (const float*)d_in[0];
    const int*   ninds    = (const int*)d_in[1];
    const float* wn       = (const float*)d_in[2];
    const float* addl     = (const float*)d_in[3];
    float*       out      = (float*)d_out;

    const int total_points = B_ * M_;            // 80000
    dim3 grid(total_points / PPB);               // 20000 blocks, 1 point/wave
    dim3 block(256);
    pconv_kernel<<<grid, block, 0, stream>>>(in_feats, ninds, wn, addl, out);
}